// Round 8
// baseline (245.546 us; speedup 1.0000x reference)
//
#include <hip/hip_runtime.h>

// Radon transform: data (1,1,512,512) f32, angles (256,) f32 -> out (1,1,256,512) f32.
// r8: BARRIER-FREE direct gather. The padded image (736x736 f32 = 2.1 MB, built
// once in d_ws) fits in every XCD's 4 MB L2, and a wave's 8-sample working set
// (~17 KB) fits L1 -- so the 4 bilinear taps are loaded straight from global
// memory (L1/L2) instead of staging tiles into LDS. This deletes the per-chunk
// {stage -> __syncthreads -> vmcnt(0)-drain -> sample -> __syncthreads} machinery
// whose synchronized drains across the 4 co-resident blocks were the ~37% idle
// (r1-r7: VALUBusy stuck 60-72%, all pipes < wall). No LDS tile, no bbox math,
// no barriers until the final 512->64 output reduce. Samples are independent ->
// deep MLP per wave; padded coords (+112) keep every tap in-bounds, branch-free.
// Per-sample cost unchanged vs r7 (~12 VALU: 2 cvt, 2 fract, mad+lshl_add addr,
// packed v_pk_fma lerps); 4 global_load_dword share one voffset via imm offsets
// 0 / 4 / 2944 / 2948 (13-bit signed imm fits).

#define HH 512
#define WW 512
#define NA 256
#define XC 64
#define NXC (WW / XC)          // 8 x-chunks
#define NW 8                   // waves per block
#define PAD 112                // >= 256*sqrt(2)-256+2
#define PW (WW + 2 * PAD)      // 736
#define PH (HH + 2 * PAD)      // 736

typedef float f32x2 __attribute__((ext_vector_type(2)));

__global__ __launch_bounds__(256) void pad_kernel(
    const float* __restrict__ img, float* __restrict__ P)
{
    const int c = blockIdx.x * 256 + threadIdx.x;
    const int r = blockIdx.y;
    if (c >= PW) return;
    const int gr = r - PAD, gc = c - PAD;
    float v = 0.0f;
    if ((unsigned)gr < (unsigned)HH && (unsigned)gc < (unsigned)WW)
        v = img[gr * WW + gc];
    P[r * PW + c] = v;
}

__device__ __forceinline__ float fract_f(float x) {
#if __has_builtin(__builtin_amdgcn_fractf)
    return __builtin_amdgcn_fractf(x);
#else
    return x - floorf(x);
#endif
}

template <bool PADDED>
__global__ __launch_bounds__(512, 8) void radon_kernel(
    const float* __restrict__ src,   // PADDED ? padded image : raw image
    const float* __restrict__ angles, float* __restrict__ out)
{
    __shared__ float red[512];       // final reduce only (2 KB)

    const int tid  = threadIdx.x;
    const int lane = tid & 63;
    const int wid  = tid >> 6;       // 0..7

    const int a  = blockIdx.x >> 3;
    const int x0 = (blockIdx.x & 7) * XC;

    float s, c;
    sincosf(angles[a], &s, &c);

    const float u   = (float)(x0 + lane) + (0.5f - 256.0f);
    const float cu  = c * u;
    const float msu = -s * u;

    f32x2 accA, accB;
    accA.x = 0.0f; accA.y = 0.0f;
    accB.x = 0.0f; accB.y = 0.0f;

    if (PADDED) {
        // padded coords: ix'' = c*u + s*vy + 255.5 + PAD  in [6.1, 729.9) -> all
        // 4 taps (ci..ci+1, ri..ri+1) inside the 736x736 padded image. >= 0, so
        // (int) == floor and fract() is exact.
        const float CK  = 255.5f + (float)PAD;
        const float bcx = cu + CK;
        const float bcy = msu + CK;

        f32x2 stepv, k2, k3, k4;
        stepv.x = s;   stepv.y = c;
        k2.x = 2.0f; k2.y = 2.0f;
        k3.x = 3.0f; k3.y = 3.0f;
        k4.x = 4.0f; k4.y = 4.0f;

#pragma unroll 1
        for (int yc = 0; yc < 8; ++yc) {
            const float vy0 = (float)(yc * 64 + wid * 8) - 255.5f;
            f32x2 crx;
            crx.x = fmaf(s, vy0, bcx);   // padded col coord
            crx.y = fmaf(c, vy0, bcy);   // padded row coord

            // 8 samples as 2 groups of 4: independent coords, one voffset per
            // sample, 4 taps via imm offsets, packed lerp math.
#pragma unroll
            for (int g = 0; g < 2; ++g) {
                f32x2 crs[4];
                crs[0] = crx;
                crs[1] = crx + stepv;
                crs[2] = __builtin_elementwise_fma(stepv, k2, crx);
                crs[3] = __builtin_elementwise_fma(stepv, k3, crx);
                crx = __builtin_elementwise_fma(stepv, k4, crx);

                int ad[4];
                float wx[4], wy[4];
#pragma unroll
                for (int i = 0; i < 4; ++i) {
                    const int ci = (int)crs[i].x;
                    const int ri = (int)crs[i].y;
                    wx[i] = fract_f(crs[i].x);
                    wy[i] = fract_f(crs[i].y);
                    __builtin_assume(ci >= 0 && ci < PW - 1);
                    __builtin_assume(ri >= 0 && ri < PH - 1);
                    ad[i] = ri * PW + ci;
                }

                f32x2 top[4], bot[4];
#pragma unroll
                for (int i = 0; i < 4; ++i) {
                    // global_load_dword x4, imm offsets 0 / 4 / 2944 / 2948
                    top[i].x = src[ad[i]];
                    top[i].y = src[ad[i] + 1];
                    bot[i].x = src[ad[i] + PW];
                    bot[i].y = src[ad[i] + PW + 1];
                }

#pragma unroll
                for (int i = 0; i < 4; ++i) {
                    f32x2 wyv;
                    wyv.x = wy[i];
                    wyv.y = wy[i];
                    const f32x2 pv =
                        __builtin_elementwise_fma(wyv, bot[i] - top[i], top[i]);
                    f32x2 wxv;
                    wxv.x = 1.0f - wx[i];
                    wxv.y = wx[i];
                    if (i & 1) accB = __builtin_elementwise_fma(wxv, pv, accB);
                    else       accA = __builtin_elementwise_fma(wxv, pv, accA);
                }
            }
        }
    } else {
        // fallback (no workspace): raw image, per-tap bounds checks
        const float bcx = cu + 255.5f;
        const float bcy = msu + 255.5f;
#pragma unroll 1
        for (int yc = 0; yc < 8; ++yc) {
            const float vy0 = (float)(yc * 64 + wid * 8) - 255.5f;
#pragma unroll
            for (int i = 0; i < 8; ++i) {
                const float vy = vy0 + (float)i;
                const float cx = fmaf(s, vy, bcx);
                const float cy = fmaf(c, vy, bcy);
                const float xf = floorf(cx);
                const float yf = floorf(cy);
                const float wx1 = cx - xf;
                const float wy1 = cy - yf;
                const int xi = (int)xf;
                const int yi = (int)yf;
                auto tap = [&](int yy, int xx) -> float {
                    const bool ok = ((unsigned)xx < (unsigned)WW) &
                                    ((unsigned)yy < (unsigned)HH);
                    const int yyc = min(max(yy, 0), HH - 1);
                    const int xxc = min(max(xx, 0), WW - 1);
                    const float t = src[yyc * WW + xxc];
                    return ok ? t : 0.0f;
                };
                const float v00 = tap(yi, xi),     v01 = tap(yi, xi + 1);
                const float v10 = tap(yi + 1, xi), v11 = tap(yi + 1, xi + 1);
                const float px0 = v00 + wy1 * (v10 - v00);
                const float px1 = v01 + wy1 * (v11 - v01);
                accA.x += (1.0f - wx1) * px0;
                accA.y += wx1 * px1;
            }
        }
    }

    // reduce the 8 y-groups per column and store (each block owns its outputs)
    red[tid] = (accA.x + accB.x) + (accA.y + accB.y);
    __syncthreads();
    if (tid < 64) {
        float r = red[tid];
#pragma unroll
        for (int k = 1; k < NW; ++k) r += red[k * 64 + tid];
        out[a * WW + x0 + tid] = r;
    }
}

extern "C" void kernel_launch(void* const* d_in, const int* in_sizes, int n_in,
                              void* d_out, int out_size, void* d_ws, size_t ws_size,
                              hipStream_t stream) {
    const float* img    = (const float*)d_in[0];
    const float* angles = (const float*)d_in[1];
    float* out = (float*)d_out;
    float* P   = (float*)d_ws;

    const bool padded = (ws_size >= (size_t)PW * PH * sizeof(float));

    if (padded) {
        pad_kernel<<<dim3((PW + 255) / 256, PH), 256, 0, stream>>>(img, P);
        radon_kernel<true><<<dim3(NA * NXC), 512, 0, stream>>>(P, angles, out);
    } else {
        radon_kernel<false><<<dim3(NA * NXC), 512, 0, stream>>>(img, angles, out);
    }
}

// Round 9
// 113.383 us; speedup vs baseline: 2.1656x; 2.1656x over previous
//
#include <hip/hip_runtime.h>
#include <hip/hip_fp16.h>

// Radon transform: data (1,1,512,512) f32, angles (256,) f32 -> out (1,1,256,512) f32.
// r9: r7 structure (LDS tile gather; 35.8 KB single buffer, 4 blocks/CU = 32
// waves; stride 95/97 by sign(c)) with the LDS traffic HALVED. r7's budget
// showed the LDS pipe saturated (2x ds_read2_b32/sample = ~95k cy + 31k conflict
// + 18k staging ~= the 145k wall; VALU 92k hides in its shadow). The padded
// image is now packed as u32 dwords: dword [r][c] = (fp16 v[r][c], fp16 v[r][c+1]).
// All 4 bilinear taps land in TWO dwords at (ad, ad+STRIDE) -> ONE ds_read2_b32
// per sample. Unpack = 4 v_cvt_f32_f16; lerp math stays f32 (only added error is
// fp16 storage quantization, ~0.06 max vs 0.25 tolerance). Staging bytes halve.
// r8 lesson: direct L1/L2 gather is TA-bound (scattered lanes -> ~30 cyc/wave
// load, 203 us); LDS is the only pipe that eats 64 scattered lane addrs/instr.

#define HH 512
#define WW 512
#define NA 256
#define XC 64
#define YC 64
#define NXC (WW / XC)          // 8 x-chunks
#define NYC (HH / YC)          // 8 y-chunks
#define NW 8                   // waves per block
#define ROWS_MAX 92
#define SMAX 97
#define PAD 112                // >= 256*sqrt(2)-256+2
#define PW (WW + 2 * PAD)      // 736
#define PH (HH + 2 * PAD)      // 736

typedef float f32x2 __attribute__((ext_vector_type(2)));

// padded + fp16-PAIR-packed image: dword [r][c] = (h(v[r][c]), h(v[r][c+1]))
__global__ __launch_bounds__(256) void pad16_kernel(
    const float* __restrict__ img, unsigned int* __restrict__ P)
{
    const int c = blockIdx.x * 256 + threadIdx.x;
    const int r = blockIdx.y;
    if (c >= PW) return;
    const int gr = r - PAD, gc = c - PAD;
    float v0 = 0.0f, v1 = 0.0f;
    if ((unsigned)gr < (unsigned)HH) {
        if ((unsigned)gc < (unsigned)WW)       v0 = img[gr * WW + gc];
        if ((unsigned)(gc + 1) < (unsigned)WW) v1 = img[gr * WW + gc + 1];
    }
    const unsigned int lo = __half_as_ushort(__float2half_rn(v0));
    const unsigned int hi = __half_as_ushort(__float2half_rn(v1));
    P[r * PW + c] = lo | (hi << 16);
}

__device__ __forceinline__ float fract_f(float x) {
#if __has_builtin(__builtin_amdgcn_fractf)
    return __builtin_amdgcn_fractf(x);
#else
    return x - floorf(x);
#endif
}

__device__ __forceinline__ f32x2 unpack_h2(unsigned int p) {
    f32x2 r;
    r.x = __half2float(__ushort_as_half((unsigned short)(p & 0xffffu)));
    r.y = __half2float(__ushort_as_half((unsigned short)(p >> 16)));
    return r;
}

template <int STRIDE>
__device__ __forceinline__ void sample_chunk(
    const unsigned int* __restrict__ tb, const int c_lo, const int r_lo,
    const float v0, const float s, const float c, const float u, const int wid,
    f32x2& accA, f32x2& accB)
{
    const float bc = fmaf(c, u, 255.5f - (float)c_lo);
    const float br = fmaf(-s, u, 255.5f - (float)r_lo);
    const float vy0 = v0 + (float)(wid * 8);

    f32x2 base, stepv;
    base.x = fmaf(s, vy0, bc);     // local col coord, >= 0
    base.y = fmaf(c, vy0, br);     // local row coord, >= 0
    stepv.x = s;
    stepv.y = c;

    f32x2 k2, k3, k4;
    k2.x = 2.0f; k2.y = 2.0f;
    k3.x = 3.0f; k3.y = 3.0f;
    k4.x = 4.0f; k4.y = 4.0f;

    // 8 samples as 2 groups of 4. Per sample: ONE ds_read2_b32 (offsets
    // 0, STRIDE -- both 8-bit dword imms) fetches all 4 taps as fp16 pairs;
    // 4x v_cvt_f32_f16 unpack; lerp math in f32 exactly as r7.
#pragma unroll
    for (int g = 0; g < 2; ++g) {
        f32x2 crs[4];
        crs[0] = base;
        crs[1] = base + stepv;
        crs[2] = __builtin_elementwise_fma(stepv, k2, base);
        crs[3] = __builtin_elementwise_fma(stepv, k3, base);
        base = __builtin_elementwise_fma(stepv, k4, base);

        int ad[4];
        float wx[4], wy[4];
#pragma unroll
        for (int i = 0; i < 4; ++i) {
            const int ci = (int)crs[i].x;        // == floor for >= 0
            const int ri = (int)crs[i].y;
            wx[i] = fract_f(crs[i].x);
            wy[i] = fract_f(crs[i].y);
            __builtin_assume(ri >= 0 && ri < ROWS_MAX);
            __builtin_assume(ci >= 0 && ci < SMAX);
            ad[i] = ri * STRIDE + ci;
        }

        unsigned int pt[4], pb[4];
#pragma unroll
        for (int i = 0; i < 4; ++i) {
            pt[i] = tb[ad[i]];            // ds_read2_b32 offset0:0 offset1:STRIDE
            pb[i] = tb[ad[i] + STRIDE];
        }
        __builtin_amdgcn_sched_barrier(0);

        __builtin_amdgcn_s_setprio(1);
#pragma unroll
        for (int i = 0; i < 4; ++i) {
            const f32x2 top = unpack_h2(pt[i]);
            const f32x2 bot = unpack_h2(pb[i]);
            f32x2 wyv;
            wyv.x = wy[i];
            wyv.y = wy[i];
            const f32x2 pv = __builtin_elementwise_fma(wyv, bot - top, top);
            f32x2 wxv;
            wxv.x = 1.0f - wx[i];
            wxv.y = wx[i];
            if (i & 1) accB = __builtin_elementwise_fma(wxv, pv, accB);
            else       accA = __builtin_elementwise_fma(wxv, pv, accA);
        }
        __builtin_amdgcn_s_setprio(0);
    }
}

// fp32 fallback sampling (no workspace): r7 code path, tile holds f32 bits
template <int STRIDE>
__device__ __forceinline__ void sample_chunk_f32(
    const float* __restrict__ tb, const int c_lo, const int r_lo, const float v0,
    const float s, const float c, const float u, const int wid,
    f32x2& accA, f32x2& accB)
{
    const float bc = fmaf(c, u, 255.5f - (float)c_lo);
    const float br = fmaf(-s, u, 255.5f - (float)r_lo);
    const float vy0 = v0 + (float)(wid * 8);

    f32x2 crx, stepv;
    crx.x = fmaf(s, vy0, bc);
    crx.y = fmaf(c, vy0, br);
    stepv.x = s;
    stepv.y = c;

#pragma unroll
    for (int i = 0; i < 8; ++i) {
        const int ci = (int)crx.x;
        const int ri = (int)crx.y;
        const float wx1 = fract_f(crx.x);
        const float wy1 = fract_f(crx.y);
        __builtin_assume(ri >= 0 && ri < ROWS_MAX);
        __builtin_assume(ci >= 0 && ci < SMAX);
        const int ad = ri * STRIDE + ci;
        f32x2 top, bot;
        top.x = tb[ad];
        top.y = tb[ad + 1];
        bot.x = tb[ad + STRIDE];
        bot.y = tb[ad + STRIDE + 1];
        f32x2 wyv;
        wyv.x = wy1;
        wyv.y = wy1;
        const f32x2 pv = __builtin_elementwise_fma(wyv, bot - top, top);
        f32x2 wxv;
        wxv.x = 1.0f - wx1;
        wxv.y = wx1;
        if (i & 1) accB = __builtin_elementwise_fma(wxv, pv, accB);
        else       accA = __builtin_elementwise_fma(wxv, pv, accA);
        crx += stepv;
    }
}

template <bool PADDED, int STRIDE>
__device__ __forceinline__ void radon_body(
    const void* __restrict__ srcv, unsigned int* __restrict__ tile,
    const float s, const float c, const int lane, const int wid, const int x0,
    f32x2& accA, f32x2& accB)
{
    constexpr bool CPOS = (STRIDE == 95);   // stride picked by sign(c)

    const float u  = (float)(x0 + lane) + (0.5f - 256.0f);
    const float u0 = (float)x0 + (0.5f - 256.0f);
    const float u1 = u0 + (float)(XC - 1);

    // origin-shifted padded base (dword units): valid for indices in [-PAD, WW+PAD)
    const unsigned int* __restrict__ Porg =
        PADDED ? ((const unsigned int*)srcv + PAD * PW + PAD) : nullptr;
    const float* __restrict__ raw = PADDED ? nullptr : (const float*)srcv;

    for (int yc = 0; yc < NYC; ++yc) {
        const float v0 = (float)(yc * YC) + (0.5f - 256.0f);
        const float v1 = v0 + (float)(YC - 1);

        // sign(c) known at compile time (s >= 0 always): each bbox bound is
        // one affine expression -- no fmin/fmax trees (HW-verified r3/r4).
        float cx_min, cx_max, rx_min, rx_max;
        if (CPOS) {
            cx_min = fmaf(c, u0, fmaf(s, v0, 255.5f));
            cx_max = fmaf(c, u1, fmaf(s, v1, 255.5f));
            rx_min = fmaf(-s, u1, fmaf(c, v0, 255.5f));
            rx_max = fmaf(-s, u0, fmaf(c, v1, 255.5f));
        } else {
            cx_min = fmaf(c, u1, fmaf(s, v0, 255.5f));
            cx_max = fmaf(c, u0, fmaf(s, v1, 255.5f));
            rx_min = fmaf(-s, u1, fmaf(c, v1, 255.5f));
            rx_max = fmaf(-s, u0, fmaf(c, v0, 255.5f));
        }

        const int c_lo = (int)floorf(cx_min);
        const int c_hi = (int)floorf(cx_max) + 1;
        const int r_lo = (int)floorf(rx_min);
        const int r_hi = (int)floorf(rx_max) + 1;
        const int bh = min(r_hi - r_lo + 1, ROWS_MAX);

        // chunk entirely outside image -> contributes exactly 0 (zero padding)
        if (c_lo > WW - 1 || c_hi < 0 || r_lo > HH - 1 || r_hi < 0) continue;

        __syncthreads();   // previous chunk's sampling must finish before overwrite

        if (PADDED) {
            // one global_load_lds_dwordx4 per bbox row: lanes 0..22 each move
            // 16 B -> LDS row base + lane*16 (368 B covers 92 pair-dwords;
            // <= STRIDE*4). Pair-dword ci holds taps (ci, ci+1) -> needed dword
            // range is [c_lo, c_hi-1], width <= 91 < 92. All staged addresses
            // inside the padded image ([-106,617] in [-112,624)).
            if (lane < 23) {
                const unsigned int* g = Porg + (r_lo + wid) * PW + c_lo + lane * 4;
                unsigned int* l = &tile[wid * STRIDE];
                for (int r = wid; r < bh; r += NW) {
                    __builtin_amdgcn_global_load_lds(
                        (__attribute__((address_space(1))) const void*)g,
                        (__attribute__((address_space(3))) void*)l, 16, 0, 0);
                    g += NW * PW;
                    l += NW * STRIDE;
                }
            }
        } else {
            const int bw = min(c_hi - c_lo + 1, SMAX);
            float* tf = (float*)tile;
            for (int r = wid; r < bh; r += NW) {
                const int gr = r_lo + r;
                const bool row_ok = ((unsigned)gr < (unsigned)HH);
                const float* __restrict__ rowp = raw + gr * WW;
                for (int cc = lane; cc < bw; cc += 64) {
                    const int gc = c_lo + cc;
                    float v = 0.0f;
                    if (row_ok) {
                        const int gcl = min(max(gc, 0), WW - 1);
                        const float t = rowp[gcl];
                        v = ((unsigned)gc < (unsigned)WW) ? t : 0.0f;
                    }
                    tf[r * STRIDE + cc] = v;
                }
            }
        }

        __syncthreads();

        if (PADDED)
            sample_chunk<STRIDE>(tile, c_lo, r_lo, v0, s, c, u, wid, accA, accB);
        else
            sample_chunk_f32<STRIDE>((const float*)tile, c_lo, r_lo, v0, s, c, u,
                                     wid, accA, accB);
    }
}

template <bool PADDED>
__global__ __launch_bounds__(512, 8) void radon_kernel(
    const void* __restrict__ src,    // PADDED ? packed padded image : raw image
    const float* __restrict__ angles, float* __restrict__ out)
{
    __shared__ unsigned int tile[ROWS_MAX * SMAX];  // 35.7 KB -> 4 blocks/CU

    const int tid  = threadIdx.x;
    const int lane = tid & 63;
    const int wid  = tid >> 6;     // 0..7

    const int a  = blockIdx.x >> 3;
    const int x0 = (blockIdx.x & 7) * XC;

    float s, c;
    sincosf(angles[a], &s, &c);

    // bank = (ri*stride + ci) % 32; stride 95 (== -1 mod 32) -> bank step c+s,
    // stride 97 (== +1) -> bank step c-s. s>=0: pick so |step| >= 1 always.
    // Block-uniform branch (same angle for whole block) -> __syncthreads safe.
    f32x2 accA, accB;
    accA.x = 0.0f; accA.y = 0.0f;
    accB.x = 0.0f; accB.y = 0.0f;
    if (c >= 0.0f)
        radon_body<PADDED, 95>(src, tile, s, c, lane, wid, x0, accA, accB);
    else
        radon_body<PADDED, 97>(src, tile, s, c, lane, wid, x0, accA, accB);

    // reduce the 8 y-groups per column and store (each block owns its outputs)
    __syncthreads();
    float* red = (float*)tile;
    red[tid] = (accA.x + accB.x) + (accA.y + accB.y);
    __syncthreads();
    if (tid < 64) {
        float r = red[tid];
#pragma unroll
        for (int k = 1; k < NW; ++k) r += red[k * 64 + tid];
        out[a * WW + x0 + tid] = r;
    }
}

extern "C" void kernel_launch(void* const* d_in, const int* in_sizes, int n_in,
                              void* d_out, int out_size, void* d_ws, size_t ws_size,
                              hipStream_t stream) {
    const float* img    = (const float*)d_in[0];
    const float* angles = (const float*)d_in[1];
    float* out = (float*)d_out;

    const bool padded = (ws_size >= (size_t)PW * PH * sizeof(unsigned int));

    if (padded) {
        unsigned int* P16 = (unsigned int*)d_ws;
        pad16_kernel<<<dim3((PW + 255) / 256, PH), 256, 0, stream>>>(img, P16);
        radon_kernel<true><<<dim3(NA * NXC), 512, 0, stream>>>(P16, angles, out);
    } else {
        radon_kernel<false><<<dim3(NA * NXC), 512, 0, stream>>>(img, angles, out);
    }
}

// Round 10
// 110.042 us; speedup vs baseline: 2.2314x; 1.0304x over previous
//
#include <hip/hip_runtime.h>

// Radon transform: data (1,1,512,512) f32, angles (256,) f32 -> out (1,1,256,512) f32.
// r10: r7 structure (f32 LDS tile gather; 35.8 KB single buffer, 4 blocks/CU =
// 32 waves; stride 95/97 by sign(c); global_load_lds staging) with the 4-sample
// read batch FORCED via inline asm. r5/r7 asked the compiler to batch the 8
// ds_read2_b32 per group and it re-serialized both times (VGPR pinned at 24 ->
// ~1 sample in flight -> each sample eats its own lgkm latency). Now: addresses
// in C, ONE asm volatile block issuing 8 ds_read2_b32 (t0,b0,t1,b1,t2,b2,t3,b3)
// into early-clobber VGPR pairs, then a rolling wait pipeline lgkmcnt(6)/4/2/0
// with sched_barrier(0) after each wait (rule-18: hipcc hoists reg-only math
// past inline-asm waitcnt unless fenced). r9 lesson: fp16 halved LDS traffic &
// conflicts, wall ROSE -> LDS throughput is NOT the wall; revert to f32 taps.

#define HH 512
#define WW 512
#define NA 256
#define XC 64
#define YC 64
#define NXC (WW / XC)          // 8 x-chunks
#define NYC (HH / YC)          // 8 y-chunks
#define NW 8                   // waves per block
#define ROWS_MAX 92
#define SMAX 97
#define PAD 112                // >= 256*sqrt(2)-256+2
#define PW (WW + 2 * PAD)      // 736
#define PH (HH + 2 * PAD)      // 736

typedef float f32x2 __attribute__((ext_vector_type(2)));

__global__ __launch_bounds__(256) void pad_kernel(
    const float* __restrict__ img, float* __restrict__ P)
{
    const int c = blockIdx.x * 256 + threadIdx.x;
    const int r = blockIdx.y;
    if (c >= PW) return;
    const int gr = r - PAD, gc = c - PAD;
    float v = 0.0f;
    if ((unsigned)gr < (unsigned)HH && (unsigned)gc < (unsigned)WW)
        v = img[gr * WW + gc];
    P[r * PW + c] = v;
}

__device__ __forceinline__ float fract_f(float x) {
#if __has_builtin(__builtin_amdgcn_fractf)
    return __builtin_amdgcn_fractf(x);
#else
    return x - floorf(x);
#endif
}

template <int STRIDE>
__device__ __forceinline__ void sample_chunk(
    const float* __restrict__ tb, const int c_lo, const int r_lo, const float v0,
    const float s, const float c, const float u, const int wid,
    f32x2& accA, f32x2& accB)
{
    const float bc = fmaf(c, u, 255.5f - (float)c_lo);
    const float br = fmaf(-s, u, 255.5f - (float)r_lo);
    const float vy0 = v0 + (float)(wid * 8);

    f32x2 base, stepv;
    base.x = fmaf(s, vy0, bc);     // local col coord, >= 0
    base.y = fmaf(c, vy0, br);     // local row coord, >= 0
    stepv.x = s;
    stepv.y = c;

    f32x2 k2, k3, k4;
    k2.x = 2.0f; k2.y = 2.0f;
    k3.x = 3.0f; k3.y = 3.0f;
    k4.x = 4.0f; k4.y = 4.0f;

    // LDS byte-offset base of the tile (AS3 cast pattern = same as the
    // global_load_lds destination cast, HW-verified in r1..r9).
    const unsigned lds0 =
        (unsigned)(unsigned long long)(__attribute__((address_space(3))) const void*)tb;

#pragma unroll
    for (int g = 0; g < 2; ++g) {
        f32x2 crs[4];
        crs[0] = base;
        crs[1] = base + stepv;
        crs[2] = __builtin_elementwise_fma(stepv, k2, base);
        crs[3] = __builtin_elementwise_fma(stepv, k3, base);
        base = __builtin_elementwise_fma(stepv, k4, base);

        unsigned at[4], ab[4];
        float wx[4], wy[4];
#pragma unroll
        for (int i = 0; i < 4; ++i) {
            const int ci = (int)crs[i].x;        // == floor for >= 0
            const int ri = (int)crs[i].y;
            wx[i] = fract_f(crs[i].x);
            wy[i] = fract_f(crs[i].y);
            __builtin_assume(ri >= 0 && ri < ROWS_MAX);
            __builtin_assume(ci >= 0 && ci < SMAX);
            at[i] = lds0 + (unsigned)(ri * STRIDE + ci) * 4u;
            ab[i] = at[i] + (unsigned)(STRIDE * 4);
        }

        // All 8 ds_read2_b32 issued back-to-back; the register allocator
        // CANNOT re-serialize an asm block (r5/r7: compiler refused at source
        // level, VGPR stuck at 24). Early-clobber: outputs written while later
        // addresses still live.
        f32x2 t0, b0, t1, b1, t2, b2, t3, b3;
        asm volatile(
            "ds_read2_b32 %0, %8  offset0:0 offset1:1\n\t"
            "ds_read2_b32 %1, %12 offset0:0 offset1:1\n\t"
            "ds_read2_b32 %2, %9  offset0:0 offset1:1\n\t"
            "ds_read2_b32 %3, %13 offset0:0 offset1:1\n\t"
            "ds_read2_b32 %4, %10 offset0:0 offset1:1\n\t"
            "ds_read2_b32 %5, %14 offset0:0 offset1:1\n\t"
            "ds_read2_b32 %6, %11 offset0:0 offset1:1\n\t"
            "ds_read2_b32 %7, %15 offset0:0 offset1:1"
            : "=&v"(t0), "=&v"(b0), "=&v"(t1), "=&v"(b1),
              "=&v"(t2), "=&v"(b2), "=&v"(t3), "=&v"(b3)
            : "v"(at[0]), "v"(at[1]), "v"(at[2]), "v"(at[3]),
              "v"(ab[0]), "v"(ab[1]), "v"(ab[2]), "v"(ab[3]));

        // Rolling wait pipeline: sample i's math waits only for its own pair
        // (outstanding = 8 - 2*(i+1)). sched_barrier(0) after each wait is the
        // rule-18 fence (math must not hoist above its waitcnt).
#define LERP_STEP(TT, BB, I, ACC)                                         \
        {                                                                 \
            f32x2 wyv; wyv.x = wy[I]; wyv.y = wy[I];                      \
            const f32x2 pv =                                              \
                __builtin_elementwise_fma(wyv, (BB) - (TT), (TT));        \
            f32x2 wxv; wxv.x = 1.0f - wx[I]; wxv.y = wx[I];               \
            ACC = __builtin_elementwise_fma(wxv, pv, ACC);                \
        }

        asm volatile("s_waitcnt lgkmcnt(6)");
        __builtin_amdgcn_sched_barrier(0);
        LERP_STEP(t0, b0, 0, accA);
        asm volatile("s_waitcnt lgkmcnt(4)");
        __builtin_amdgcn_sched_barrier(0);
        LERP_STEP(t1, b1, 1, accB);
        asm volatile("s_waitcnt lgkmcnt(2)");
        __builtin_amdgcn_sched_barrier(0);
        LERP_STEP(t2, b2, 2, accA);
        asm volatile("s_waitcnt lgkmcnt(0)");
        __builtin_amdgcn_sched_barrier(0);
        LERP_STEP(t3, b3, 3, accB);
#undef LERP_STEP
    }
}

template <bool PADDED, int STRIDE>
__device__ __forceinline__ void radon_body(
    const float* __restrict__ src, float* __restrict__ tile,
    const float s, const float c, const int lane, const int wid, const int x0,
    f32x2& accA, f32x2& accB)
{
    constexpr bool CPOS = (STRIDE == 95);   // stride picked by sign(c)

    const float u  = (float)(x0 + lane) + (0.5f - 256.0f);
    const float u0 = (float)x0 + (0.5f - 256.0f);
    const float u1 = u0 + (float)(XC - 1);

    // origin-shifted padded base: valid for row/col indices in [-PAD, WW+PAD)
    const float* __restrict__ Porg = PADDED ? (src + PAD * PW + PAD) : src;

    for (int yc = 0; yc < NYC; ++yc) {
        const float v0 = (float)(yc * YC) + (0.5f - 256.0f);
        const float v1 = v0 + (float)(YC - 1);

        // sign(c) known at compile time (s >= 0 always): each bbox bound is
        // one affine expression -- no fmin/fmax trees (HW-verified r3/r4).
        float cx_min, cx_max, rx_min, rx_max;
        if (CPOS) {
            cx_min = fmaf(c, u0, fmaf(s, v0, 255.5f));
            cx_max = fmaf(c, u1, fmaf(s, v1, 255.5f));
            rx_min = fmaf(-s, u1, fmaf(c, v0, 255.5f));
            rx_max = fmaf(-s, u0, fmaf(c, v1, 255.5f));
        } else {
            cx_min = fmaf(c, u1, fmaf(s, v0, 255.5f));
            cx_max = fmaf(c, u0, fmaf(s, v1, 255.5f));
            rx_min = fmaf(-s, u1, fmaf(c, v1, 255.5f));
            rx_max = fmaf(-s, u0, fmaf(c, v0, 255.5f));
        }

        const int c_lo = (int)floorf(cx_min);
        const int c_hi = (int)floorf(cx_max) + 1;
        const int r_lo = (int)floorf(rx_min);
        const int r_hi = (int)floorf(rx_max) + 1;
        const int bh = min(r_hi - r_lo + 1, ROWS_MAX);

        // chunk entirely outside image -> contributes exactly 0 (zero padding)
        if (c_lo > WW - 1 || c_hi < 0 || r_lo > HH - 1 || r_hi < 0) continue;

        __syncthreads();   // previous chunk's sampling must finish before overwrite

        if (PADDED) {
            // one global_load_lds_dwordx4 per bbox row: lanes 0..22 each move
            // 16 B -> LDS row base + lane*16 (368 B covers 92 dwords; <= STRIDE*4).
            // All staged addresses inside the padded image ([-106,617] in [-112,624)).
            if (lane < 23) {
                const float* g = Porg + (r_lo + wid) * PW + c_lo + lane * 4;
                float* l = &tile[wid * STRIDE];
                for (int r = wid; r < bh; r += NW) {
                    __builtin_amdgcn_global_load_lds(
                        (__attribute__((address_space(1))) const void*)g,
                        (__attribute__((address_space(3))) void*)l, 16, 0, 0);
                    g += NW * PW;
                    l += NW * STRIDE;
                }
            }
        } else {
            const int bw = min(c_hi - c_lo + 1, SMAX);
            for (int r = wid; r < bh; r += NW) {
                const int gr = r_lo + r;
                const bool row_ok = ((unsigned)gr < (unsigned)HH);
                const float* __restrict__ rowp = src + gr * WW;
                for (int cc = lane; cc < bw; cc += 64) {
                    const int gc = c_lo + cc;
                    float v = 0.0f;
                    if (row_ok) {
                        const int gcl = min(max(gc, 0), WW - 1);
                        const float t = rowp[gcl];
                        v = ((unsigned)gc < (unsigned)WW) ? t : 0.0f;
                    }
                    tile[r * STRIDE + cc] = v;
                }
            }
        }

        __syncthreads();

        sample_chunk<STRIDE>(tile, c_lo, r_lo, v0, s, c, u, wid, accA, accB);
    }
}

template <bool PADDED>
__global__ __launch_bounds__(512, 8) void radon_kernel(
    const float* __restrict__ src,   // PADDED ? padded image : raw image
    const float* __restrict__ angles, float* __restrict__ out)
{
    __shared__ float tile[ROWS_MAX * SMAX];   // 35.7 KB -> 4 blocks/CU (32 waves)

    const int tid  = threadIdx.x;
    const int lane = tid & 63;
    const int wid  = tid >> 6;     // 0..7

    const int a  = blockIdx.x >> 3;
    const int x0 = (blockIdx.x & 7) * XC;

    float s, c;
    sincosf(angles[a], &s, &c);

    // bank = (ri*stride + ci) % 32; stride 95 (== -1 mod 32) -> bank step c+s,
    // stride 97 (== +1) -> bank step c-s. s>=0: pick so |step| >= 1 always.
    // Block-uniform branch (same angle for whole block) -> __syncthreads safe.
    f32x2 accA, accB;
    accA.x = 0.0f; accA.y = 0.0f;
    accB.x = 0.0f; accB.y = 0.0f;
    if (c >= 0.0f)
        radon_body<PADDED, 95>(src, tile, s, c, lane, wid, x0, accA, accB);
    else
        radon_body<PADDED, 97>(src, tile, s, c, lane, wid, x0, accA, accB);

    // reduce the 8 y-groups per column and store (each block owns its outputs)
    __syncthreads();
    tile[tid] = (accA.x + accB.x) + (accA.y + accB.y);
    __syncthreads();
    if (tid < 64) {
        float r = tile[tid];
#pragma unroll
        for (int k = 1; k < NW; ++k) r += tile[k * 64 + tid];
        out[a * WW + x0 + tid] = r;
    }
}

extern "C" void kernel_launch(void* const* d_in, const int* in_sizes, int n_in,
                              void* d_out, int out_size, void* d_ws, size_t ws_size,
                              hipStream_t stream) {
    const float* img    = (const float*)d_in[0];
    const float* angles = (const float*)d_in[1];
    float* out = (float*)d_out;
    float* P   = (float*)d_ws;

    const bool padded = (ws_size >= (size_t)PW * PH * sizeof(float));

    if (padded) {
        pad_kernel<<<dim3((PW + 255) / 256, PH), 256, 0, stream>>>(img, P);
        radon_kernel<true><<<dim3(NA * NXC), 512, 0, stream>>>(P, angles, out);
    } else {
        radon_kernel<false><<<dim3(NA * NXC), 512, 0, stream>>>(img, angles, out);
    }
}